// Round 1
// baseline (1188.627 us; speedup 1.0000x reference)
//
#include <hip/hip_runtime.h>
#include <stdint.h>
#include <stddef.h>

// Narrow MHA: B=8, S=1024, D=512 (per head), H=8.
// Pipeline: fp16 MFMA GEMMs (16x16x32_f16), fp32 softmax, outputs fp32.
typedef _Float16 h16;
typedef __attribute__((ext_vector_type(4))) _Float16 h16x4;
typedef __attribute__((ext_vector_type(8))) _Float16 h16x8;
typedef __attribute__((ext_vector_type(4))) float f32x4;

#define MFMA16(a, b, c) __builtin_amdgcn_mfma_f32_16x16x32_f16((a), (b), (c), 0, 0, 0)

#define NB 8
#define SEQ 1024
#define DEP 512
#define NH 8
#define HD 4096  /* NH*DEP */
#define BS 8192  /* NB*SEQ */

static __device__ __forceinline__ void gload_lds16(const void* g, void* l) {
  // async global->LDS, 16B per lane; LDS dest = wave-uniform base + lane*16
  __builtin_amdgcn_global_load_lds((__attribute__((address_space(1))) void*)(g),
                                   (__attribute__((address_space(3))) void*)(l),
                                   16, 0, 0);
}

static __device__ __forceinline__ h16 f2h(float f) { return (h16)f; }

// ---------------- elementwise fp32 -> fp16 ----------------
__global__ __launch_bounds__(256) void k_conv(const float* __restrict__ in,
                                              h16* __restrict__ out, int n4) {
  int i = blockIdx.x * 256 + threadIdx.x;
  if (i < n4) {
    float4 f = ((const float4*)in)[i];
    h16x4 o = { f2h(f.x), f2h(f.y), f2h(f.z), f2h(f.w) };
    ((h16x4*)out)[i] = o;
  }
}

// ---------------- transpose + convert: in (R x C) fp32 -> out (C x R) fp16 ----------------
__global__ __launch_bounds__(256) void k_transpose(const float* __restrict__ in,
                                                   h16* __restrict__ out, int R, int C) {
  __shared__ float t[32][33];
  int c0 = blockIdx.x * 32, r0 = blockIdx.y * 32;
  int tx = threadIdx.x & 31, ty = threadIdx.x >> 5;  // ty 0..7
  for (int p = 0; p < 4; ++p)
    t[ty + p * 8][tx] = in[(size_t)(r0 + ty + p * 8) * C + c0 + tx];
  __syncthreads();
  for (int p = 0; p < 4; ++p)
    out[(size_t)(c0 + ty + p * 8) * R + r0 + tx] = f2h(t[tx][ty + p * 8]);
}

// ---------------- NT GEMM: C[M,N] = A[M,K] * B[N,K]^T + bias ----------------
// OUT_MODE 0: f16 natural (ldc), 1: f16 V-transpose to (B,H,D,S), 2: f32 natural (ldc)
template <int OUT_MODE>
__global__ __launch_bounds__(256) void k_gemm_nt(const h16* __restrict__ A,
                                                 const h16* __restrict__ Bm,
                                                 const float* __restrict__ bias,
                                                 void* __restrict__ Cout,
                                                 int M, int N, int K, int ldc) {
  __shared__ __align__(16) h16 As[128 * 64];
  __shared__ __align__(16) h16 Bs[128 * 64];
  const int tid = threadIdx.x;
  const int lane = tid & 63;
  const int wave = tid >> 6;           // 0..3
  const int wm = (wave >> 1) * 64;
  const int wn = (wave & 1) * 64;
  const int m0 = blockIdx.x * 128;
  const int n0 = blockIdx.y * 128;

  f32x4 acc[4][4];
  for (int i = 0; i < 4; ++i)
    for (int j = 0; j < 4; ++j) acc[i][j] = (f32x4)0.0f;

  const int lrow = lane >> 3;          // 0..7
  const int lcol = (lane & 7) * 8;     // element col
  const int fr = lane & 15, qd = lane >> 4;

  for (int k0 = 0; k0 < K; k0 += 64) {
    __syncthreads();
    for (int i = 0; i < 4; ++i) {
      int g = wave * 4 + i;            // 8-row group 0..15
      int row = g * 8 + lrow;
      gload_lds16(A + (size_t)(m0 + row) * K + k0 + lcol, As + g * 512);
      gload_lds16(Bm + (size_t)(n0 + row) * K + k0 + lcol, Bs + g * 512);
    }
    __syncthreads();
    for (int kk = 0; kk < 64; kk += 32) {
      h16x8 af[4], bf[4];
      for (int i = 0; i < 4; ++i)
        af[i] = *(const h16x8*)(As + (wm + i * 16 + fr) * 64 + kk + qd * 8);
      for (int j = 0; j < 4; ++j)
        bf[j] = *(const h16x8*)(Bs + (wn + j * 16 + fr) * 64 + kk + qd * 8);
      for (int i = 0; i < 4; ++i)
        for (int j = 0; j < 4; ++j) acc[i][j] = MFMA16(af[i], bf[j], acc[i][j]);
    }
  }

  // epilogue: C/D layout col=lane&15, row=(lane>>4)*4+reg
  for (int i = 0; i < 4; ++i) {
    for (int j = 0; j < 4; ++j) {
      int mbase = m0 + wm + i * 16 + qd * 4;
      int ncol = n0 + wn + j * 16 + fr;
      float bv = bias ? bias[ncol] : 0.0f;
      if (OUT_MODE == 0) {
        h16* Cp = (h16*)Cout;
        for (int r = 0; r < 4; ++r)
          Cp[(size_t)(mbase + r) * ldc + ncol] = f2h(acc[i][j][r] + bv);
      } else if (OUT_MODE == 2) {
        float* Cp = (float*)Cout;
        for (int r = 0; r < 4; ++r)
          Cp[(size_t)(mbase + r) * ldc + ncol] = acc[i][j][r] + bv;
      } else {
        // V-transpose: row m = b*SEQ+s, col n = h*DEP+d -> Vt[((b*NH+h)*DEP+d)*SEQ+s]
        h16* Vt = (h16*)Cout;
        int bb = mbase >> 10, ss = mbase & 1023;
        int hh = ncol >> 9, dd = ncol & 511;
        size_t addr = ((size_t)((bb * NH + hh) * DEP + dd)) * SEQ + ss;
        h16x4 pk = { f2h(acc[i][j][0] + bv), f2h(acc[i][j][1] + bv),
                     f2h(acc[i][j][2] + bv), f2h(acc[i][j][3] + bv) };
        *(h16x4*)(Vt + addr) = pk;  // 4 consecutive s, 8B aligned
      }
    }
  }
}

// ---------------- scores + softmax: attn = softmax(Q K^T * scale + mask*-1e9) ----------------
// grid (S/32, H, B), block 512 (8 waves). Wave w owns cols [w*128, w*128+128).
__global__ __launch_bounds__(512) void k_scores(const h16* __restrict__ Q,
                                                const h16* __restrict__ Km,
                                                const float* __restrict__ mask,
                                                float* __restrict__ attn) {
  __shared__ __align__(16) h16 Qs[32 * 512];
  __shared__ float red[8][32];
  const int tid = threadIdx.x, lane = tid & 63, wave = tid >> 6;
  const int qt = blockIdx.x, hh = blockIdx.y, b = blockIdx.z;
  const int q0 = qt * 32;

  // stage Q tile (32 x 512) into LDS
  for (int i = 0; i < 4; ++i) {
    int row = i * 8 + wave;
    gload_lds16(Q + (size_t)(b * SEQ + q0 + row) * HD + hh * DEP + lane * 8,
                Qs + row * 512);
  }
  __syncthreads();

  const int fr = lane & 15, qd = lane >> 4;
  const int ncol0 = wave * 128;
  f32x4 acc[2][8];
  for (int i = 0; i < 2; ++i)
    for (int j = 0; j < 8; ++j) acc[i][j] = (f32x4)0.0f;

  for (int kk = 0; kk < 512; kk += 32) {
    h16x8 af0 = *(const h16x8*)(Qs + fr * 512 + kk + qd * 8);
    h16x8 af1 = *(const h16x8*)(Qs + (16 + fr) * 512 + kk + qd * 8);
    for (int j = 0; j < 8; ++j) {
      int n = ncol0 + j * 16 + fr;
      h16x8 bf = *(const h16x8*)(Km + (size_t)(b * SEQ + n) * HD + hh * DEP + kk + qd * 8);
      acc[0][j] = MFMA16(af0, bf, acc[0][j]);
      acc[1][j] = MFMA16(af1, bf, acc[1][j]);
    }
  }

  const float scale = 0.044194173824159216f;  // 1/sqrt(512)
  float rmax[2][4];
  for (int i = 0; i < 2; ++i)
    for (int r = 0; r < 4; ++r) rmax[i][r] = -3.4e38f;
  for (int i = 0; i < 2; ++i)
    for (int j = 0; j < 8; ++j)
      for (int r = 0; r < 4; ++r) {
        int lr = i * 16 + qd * 4 + r;
        int cg = ncol0 + j * 16 + fr;
        float v = acc[i][j][r] * scale +
                  mask[(size_t)(b * SEQ + q0 + lr) * SEQ + cg] * (-1e9f);
        acc[i][j][r] = v;
        rmax[i][r] = fmaxf(rmax[i][r], v);
      }
  // reduce max over the 16 lanes sharing a row group
  for (int i = 0; i < 2; ++i)
    for (int r = 0; r < 4; ++r)
      for (int off = 1; off < 16; off <<= 1)
        rmax[i][r] = fmaxf(rmax[i][r], __shfl_xor(rmax[i][r], off, 64));
  if (fr == 0)
    for (int i = 0; i < 2; ++i)
      for (int r = 0; r < 4; ++r) red[wave][i * 16 + qd * 4 + r] = rmax[i][r];
  __syncthreads();
  float gmax[2][4];
  for (int i = 0; i < 2; ++i)
    for (int r = 0; r < 4; ++r) {
      int lr = i * 16 + qd * 4 + r;
      float m = red[0][lr];
      for (int w = 1; w < 8; ++w) m = fmaxf(m, red[w][lr]);
      gmax[i][r] = m;
    }
  __syncthreads();  // before reusing red for sums

  float rsum[2][4] = {{0.f, 0.f, 0.f, 0.f}, {0.f, 0.f, 0.f, 0.f}};
  for (int i = 0; i < 2; ++i)
    for (int j = 0; j < 8; ++j)
      for (int r = 0; r < 4; ++r) {
        float e = __expf(acc[i][j][r] - gmax[i][r]);
        acc[i][j][r] = e;
        rsum[i][r] += e;
      }
  for (int i = 0; i < 2; ++i)
    for (int r = 0; r < 4; ++r)
      for (int off = 1; off < 16; off <<= 1)
        rsum[i][r] += __shfl_xor(rsum[i][r], off, 64);
  if (fr == 0)
    for (int i = 0; i < 2; ++i)
      for (int r = 0; r < 4; ++r) red[wave][i * 16 + qd * 4 + r] = rsum[i][r];
  __syncthreads();

  float* ab = attn + (size_t)(b * NH + hh) * (size_t)(SEQ * SEQ);
  for (int i = 0; i < 2; ++i)
    for (int r = 0; r < 4; ++r) {
      int lr = i * 16 + qd * 4 + r;
      float tot = 0.f;
      for (int w = 0; w < 8; ++w) tot += red[w][lr];
      float inv = 1.0f / tot;  // >= 1 always (max term contributes exp(0)=1)
      for (int j = 0; j < 8; ++j)
        ab[(size_t)(q0 + lr) * SEQ + ncol0 + j * 16 + fr] = acc[i][j][r] * inv;
    }
}

// ---------------- PV GEMM: ctx_bh = P_bh(1024x1024 fp32) @ V_bh -> ctx fp16 (B,S,H*D) ----------------
__global__ __launch_bounds__(256) void k_gemm_pv(const float* __restrict__ P,
                                                 const h16* __restrict__ Vt,
                                                 h16* __restrict__ ctx) {
  __shared__ __align__(16) h16 As[128 * 64];
  __shared__ __align__(16) h16 Bs[128 * 64];
  const int tid = threadIdx.x, lane = tid & 63, wave = tid >> 6;
  const int wm = (wave >> 1) * 64, wn = (wave & 1) * 64;
  const int m0 = blockIdx.x * 128;   // q rows
  const int n0 = blockIdx.y * 128;   // d cols
  const int bh = blockIdx.z;
  const float* Pb = P + (size_t)bh * (size_t)(SEQ * SEQ);
  const h16* Vb = Vt + (size_t)bh * (size_t)(DEP * SEQ);

  f32x4 acc[4][4];
  for (int i = 0; i < 4; ++i)
    for (int j = 0; j < 4; ++j) acc[i][j] = (f32x4)0.0f;

  const int arow = tid >> 1;              // 0..127
  const int acol = (tid & 1) * 32;
  const int lrow = lane >> 3, lcol = (lane & 7) * 8;
  const int fr = lane & 15, qd = lane >> 4;

  for (int k0 = 0; k0 < SEQ; k0 += 64) {
    __syncthreads();
    // A: fp32 -> fp16 into LDS
    const float* src = Pb + (size_t)(m0 + arow) * SEQ + k0 + acol;
    for (int u = 0; u < 8; ++u) {
      float4 f = ((const float4*)src)[u];
      h16x4 pk = { f2h(f.x), f2h(f.y), f2h(f.z), f2h(f.w) };
      *(h16x4*)(As + arow * 64 + acol + u * 4) = pk;
    }
    // B: V^T tile via async LDS load
    for (int i = 0; i < 4; ++i) {
      int g = wave * 4 + i;
      int row = g * 8 + lrow;
      gload_lds16(Vb + (size_t)(n0 + row) * SEQ + k0 + lcol, Bs + g * 512);
    }
    __syncthreads();
    for (int kk = 0; kk < 64; kk += 32) {
      h16x8 af[4], bf[4];
      for (int i = 0; i < 4; ++i)
        af[i] = *(const h16x8*)(As + (wm + i * 16 + fr) * 64 + kk + qd * 8);
      for (int j = 0; j < 4; ++j)
        bf[j] = *(const h16x8*)(Bs + (wn + j * 16 + fr) * 64 + kk + qd * 8);
      for (int i = 0; i < 4; ++i)
        for (int j = 0; j < 4; ++j) acc[i][j] = MFMA16(af[i], bf[j], acc[i][j]);
    }
  }

  const int bb = bh >> 3, hh = bh & 7;
  for (int i = 0; i < 4; ++i)
    for (int j = 0; j < 4; ++j) {
      int s = m0 + wm + i * 16 + qd * 4;
      int d = n0 + wn + j * 16 + fr;
      for (int r = 0; r < 4; ++r)
        ctx[(size_t)(bb * SEQ + s + r) * HD + hh * DEP + d] = f2h(acc[i][j][r]);
    }
}

extern "C" void kernel_launch(void* const* d_in, const int* in_sizes, int n_in,
                              void* d_out, int out_size, void* d_ws, size_t ws_size,
                              hipStream_t stream) {
  const float* v_ip = (const float*)d_in[0];
  const float* k_ip = (const float*)d_in[1];
  const float* q_ip = (const float*)d_in[2];
  const float* mask = (const float*)d_in[3];
  const float* wq = (const float*)d_in[4];
  const float* bq = (const float*)d_in[5];
  const float* wk = (const float*)d_in[6];
  const float* bk = (const float*)d_in[7];
  const float* wv = (const float*)d_in[8];
  const float* bv = (const float*)d_in[9];
  const float* wo = (const float*)d_in[10];
  const float* bo = (const float*)d_in[11];

  char* ws = (char*)d_ws;
  // workspace layout (243.3 MB total)
  h16* Qh  = (h16*)(ws + (size_t)0);          // 64 MB; reused as ctx after scores
  h16* Kh  = (h16*)(ws + (size_t)67108864);   // 64 MB
  h16* Vt  = (h16*)(ws + (size_t)134217728);  // 64 MB, layout (B,H,D,S)
  h16* xq  = (h16*)(ws + (size_t)201326592);  // 8 MB
  h16* xk  = (h16*)(ws + (size_t)209715200);
  h16* xv  = (h16*)(ws + (size_t)218103808);
  h16* WqT = (h16*)(ws + (size_t)226492416);  // 4 MB each, (N=4096, K=512)
  h16* WkT = (h16*)(ws + (size_t)230686720);
  h16* WvT = (h16*)(ws + (size_t)234881024);
  h16* WoT = (h16*)(ws + (size_t)239075328);  // (N=512, K=4096)
  h16* ctx = Qh;

  float* out = (float*)d_out;
  float* attn = out + (size_t)BS * DEP;  // attn region starts at 4,194,304 floats

  // 1) convert inputs to fp16
  k_conv<<<4096, 256, 0, stream>>>(q_ip, xq, 1048576);
  k_conv<<<4096, 256, 0, stream>>>(k_ip, xk, 1048576);
  k_conv<<<4096, 256, 0, stream>>>(v_ip, xv, 1048576);
  // 2) transpose+convert weights to NT (k-contiguous) layout
  k_transpose<<<dim3(128, 16), 256, 0, stream>>>(wq, WqT, 512, 4096);
  k_transpose<<<dim3(128, 16), 256, 0, stream>>>(wk, WkT, 512, 4096);
  k_transpose<<<dim3(128, 16), 256, 0, stream>>>(wv, WvT, 512, 4096);
  k_transpose<<<dim3(16, 128), 256, 0, stream>>>(wo, WoT, 4096, 512);
  // 3) projections
  k_gemm_nt<0><<<dim3(64, 32), 256, 0, stream>>>(xq, WqT, bq, Qh, 8192, 4096, 512, 4096);
  k_gemm_nt<0><<<dim3(64, 32), 256, 0, stream>>>(xk, WkT, bk, Kh, 8192, 4096, 512, 4096);
  k_gemm_nt<1><<<dim3(64, 32), 256, 0, stream>>>(xv, WvT, bv, Vt, 8192, 4096, 512, 0);
  // 4) scores + softmax -> attn (fp32, second output region)
  k_scores<<<dim3(32, 8, 8), 512, 0, stream>>>(Qh, Kh, mask, attn);
  // 5) ctx = attn @ V
  k_gemm_pv<<<dim3(8, 4, 64), 256, 0, stream>>>(attn, Vt, ctx);
  // 6) out = ctx @ wo + bo (fp32, first output region)
  k_gemm_nt<2><<<dim3(64, 4), 256, 0, stream>>>(ctx, WoT, bo, out, 8192, 512, 4096, 512);
}

// Round 2
// 1037.497 us; speedup vs baseline: 1.1457x; 1.1457x over previous
//
#include <hip/hip_runtime.h>
#include <stdint.h>
#include <stddef.h>

// Narrow MHA: B=8, S=1024, D=512 (per head), H=8.
// fp16 MFMA GEMMs (16x16x32_f16), fp32 softmax, fp32 outputs (out, attn).
typedef _Float16 h16;
typedef __attribute__((ext_vector_type(4))) _Float16 h16x4;
typedef __attribute__((ext_vector_type(8))) _Float16 h16x8;
typedef __attribute__((ext_vector_type(4))) float f32x4;

#define MFMA16(a, b, c) __builtin_amdgcn_mfma_f32_16x16x32_f16((a), (b), (c), 0, 0, 0)

#define NB 8
#define SEQ 1024
#define DEP 512
#define NH 8
#define HD 4096  /* NH*DEP */
#define BS 8192  /* NB*SEQ */

static __device__ __forceinline__ void gload_lds16(const void* g, void* l) {
  // async global->LDS, 16B per lane; LDS dest = wave-uniform base + lane*16
  __builtin_amdgcn_global_load_lds((__attribute__((address_space(1))) void*)(g),
                                   (__attribute__((address_space(3))) void*)(l),
                                   16, 0, 0);
}

static __device__ __forceinline__ h16 f2h(float f) { return (h16)f; }

// ---------------- fused fp32 -> fp16 for q,k,v ----------------
__global__ __launch_bounds__(256) void k_conv3(const float* __restrict__ q,
                                               const float* __restrict__ k,
                                               const float* __restrict__ v,
                                               h16* __restrict__ xq, h16* __restrict__ xk,
                                               h16* __restrict__ xv) {
  int z = blockIdx.y;
  const float* in = z == 0 ? q : (z == 1 ? k : v);
  h16* out = z == 0 ? xq : (z == 1 ? xk : xv);
  int i = blockIdx.x * 256 + threadIdx.x;  // 1048576 float4 groups
  float4 f = ((const float4*)in)[i];
  h16x4 o = { f2h(f.x), f2h(f.y), f2h(f.z), f2h(f.w) };
  ((h16x4*)out)[i] = o;
}

// ---------------- transpose + convert: in (R x C) fp32 -> out (C x R) fp16 ----------------
__global__ __launch_bounds__(256) void k_transpose(const float* __restrict__ in,
                                                   h16* __restrict__ out, int R, int C) {
  __shared__ float t[32][33];
  int c0 = blockIdx.x * 32, r0 = blockIdx.y * 32;
  int tx = threadIdx.x & 31, ty = threadIdx.x >> 5;  // ty 0..7
  for (int p = 0; p < 4; ++p)
    t[ty + p * 8][tx] = in[(size_t)(r0 + ty + p * 8) * C + c0 + tx];
  __syncthreads();
  for (int p = 0; p < 4; ++p)
    out[(size_t)(c0 + ty + p * 8) * R + r0 + tx] = f2h(t[tx][ty + p * 8]);
}

// fused 3-way transpose for wq/wk/wv (512 x 4096 each)
__global__ __launch_bounds__(256) void k_transpose3(const float* __restrict__ wq,
                                                    const float* __restrict__ wk,
                                                    const float* __restrict__ wv,
                                                    h16* __restrict__ oq, h16* __restrict__ ok,
                                                    h16* __restrict__ ov) {
  __shared__ float t[32][33];
  int z = blockIdx.z;
  const float* in = z == 0 ? wq : (z == 1 ? wk : wv);
  h16* out = z == 0 ? oq : (z == 1 ? ok : ov);
  const int R = 512, C = 4096;
  int c0 = blockIdx.x * 32, r0 = blockIdx.y * 32;
  int tx = threadIdx.x & 31, ty = threadIdx.x >> 5;
  for (int p = 0; p < 4; ++p)
    t[ty + p * 8][tx] = in[(size_t)(r0 + ty + p * 8) * C + c0 + tx];
  __syncthreads();
  for (int p = 0; p < 4; ++p)
    out[(size_t)(c0 + ty + p * 8) * R + r0 + tx] = f2h(t[tx][ty + p * 8]);
}

// ---------------- merged QKV projection GEMM ----------------
// z selects (A, W^T, bias, epilogue). C[M=8192, N=4096] = A * W^T + b.
// z<2: natural f16 out (ld=HD). z==2: V-transpose to (B,H,D,S).
__global__ __launch_bounds__(256) void k_gemm_qkv(
    const h16* __restrict__ xq, const h16* __restrict__ xk, const h16* __restrict__ xv,
    const h16* __restrict__ WqT, const h16* __restrict__ WkT, const h16* __restrict__ WvT,
    const float* __restrict__ bq, const float* __restrict__ bk, const float* __restrict__ bv,
    h16* __restrict__ Qh, h16* __restrict__ Kh, h16* __restrict__ Vt) {
  __shared__ __align__(16) h16 As[128 * 64];
  __shared__ __align__(16) h16 Bs[128 * 64];
  const int z = blockIdx.z;
  const h16* A = z == 0 ? xq : (z == 1 ? xk : xv);
  const h16* Bm = z == 0 ? WqT : (z == 1 ? WkT : WvT);
  const float* bias = z == 0 ? bq : (z == 1 ? bk : bv);
  const int K = 512;
  const int tid = threadIdx.x, lane = tid & 63, wave = tid >> 6;
  const int wm = (wave >> 1) * 64, wn = (wave & 1) * 64;
  const int m0 = blockIdx.y * 128;  // y = M tile (x fastest shares A panel)
  const int n0 = blockIdx.x * 128;

  f32x4 acc[4][4];
  for (int i = 0; i < 4; ++i)
    for (int j = 0; j < 4; ++j) acc[i][j] = (f32x4)0.0f;

  const int lrow = lane >> 3, lcol = (lane & 7) * 8;
  const int fr = lane & 15, qd = lane >> 4;

  for (int k0 = 0; k0 < K; k0 += 64) {
    __syncthreads();
    for (int i = 0; i < 4; ++i) {
      int g = wave * 4 + i;
      int row = g * 8 + lrow;
      gload_lds16(A + (size_t)(m0 + row) * K + k0 + lcol, As + g * 512);
      gload_lds16(Bm + (size_t)(n0 + row) * K + k0 + lcol, Bs + g * 512);
    }
    __syncthreads();
    for (int kk = 0; kk < 64; kk += 32) {
      h16x8 af[4], bf[4];
      for (int i = 0; i < 4; ++i)
        af[i] = *(const h16x8*)(As + (wm + i * 16 + fr) * 64 + kk + qd * 8);
      for (int j = 0; j < 4; ++j)
        bf[j] = *(const h16x8*)(Bs + (wn + j * 16 + fr) * 64 + kk + qd * 8);
      for (int i = 0; i < 4; ++i)
        for (int j = 0; j < 4; ++j) acc[i][j] = MFMA16(af[i], bf[j], acc[i][j]);
    }
  }

  h16* Cnat = z == 0 ? Qh : Kh;
  for (int i = 0; i < 4; ++i)
    for (int j = 0; j < 4; ++j) {
      int mbase = m0 + wm + i * 16 + qd * 4;
      int ncol = n0 + wn + j * 16 + fr;
      float bv2 = bias[ncol];
      if (z < 2) {
        for (int r = 0; r < 4; ++r)
          Cnat[(size_t)(mbase + r) * HD + ncol] = f2h(acc[i][j][r] + bv2);
      } else {
        int bb = mbase >> 10, ss = mbase & 1023;
        int hh = ncol >> 9, dd = ncol & 511;
        size_t addr = ((size_t)((bb * NH + hh) * DEP + dd)) * SEQ + ss;
        h16x4 pk = { f2h(acc[i][j][0] + bv2), f2h(acc[i][j][1] + bv2),
                     f2h(acc[i][j][2] + bv2), f2h(acc[i][j][3] + bv2) };
        *(h16x4*)(Vt + addr) = pk;
      }
    }
}

// ---------------- NT GEMM (out-projection): fp32 out ----------------
template <int OUT_MODE>
__global__ __launch_bounds__(256) void k_gemm_nt(const h16* __restrict__ A,
                                                 const h16* __restrict__ Bm,
                                                 const float* __restrict__ bias,
                                                 void* __restrict__ Cout,
                                                 int M, int N, int K, int ldc) {
  __shared__ __align__(16) h16 As[128 * 64];
  __shared__ __align__(16) h16 Bs[128 * 64];
  const int tid = threadIdx.x, lane = tid & 63, wave = tid >> 6;
  const int wm = (wave >> 1) * 64, wn = (wave & 1) * 64;
  const int m0 = blockIdx.y * 128;
  const int n0 = blockIdx.x * 128;

  f32x4 acc[4][4];
  for (int i = 0; i < 4; ++i)
    for (int j = 0; j < 4; ++j) acc[i][j] = (f32x4)0.0f;

  const int lrow = lane >> 3, lcol = (lane & 7) * 8;
  const int fr = lane & 15, qd = lane >> 4;

  for (int k0 = 0; k0 < K; k0 += 64) {
    __syncthreads();
    for (int i = 0; i < 4; ++i) {
      int g = wave * 4 + i;
      int row = g * 8 + lrow;
      gload_lds16(A + (size_t)(m0 + row) * K + k0 + lcol, As + g * 512);
      gload_lds16(Bm + (size_t)(n0 + row) * K + k0 + lcol, Bs + g * 512);
    }
    __syncthreads();
    for (int kk = 0; kk < 64; kk += 32) {
      h16x8 af[4], bf[4];
      for (int i = 0; i < 4; ++i)
        af[i] = *(const h16x8*)(As + (wm + i * 16 + fr) * 64 + kk + qd * 8);
      for (int j = 0; j < 4; ++j)
        bf[j] = *(const h16x8*)(Bs + (wn + j * 16 + fr) * 64 + kk + qd * 8);
      for (int i = 0; i < 4; ++i)
        for (int j = 0; j < 4; ++j) acc[i][j] = MFMA16(af[i], bf[j], acc[i][j]);
    }
  }

  for (int i = 0; i < 4; ++i)
    for (int j = 0; j < 4; ++j) {
      int mbase = m0 + wm + i * 16 + qd * 4;
      int ncol = n0 + wn + j * 16 + fr;
      float bv2 = bias ? bias[ncol] : 0.0f;
      float* Cp = (float*)Cout;
      for (int r = 0; r < 4; ++r)
        Cp[(size_t)(mbase + r) * ldc + ncol] = acc[i][j][r] + bv2;
    }
}

// ---------------- scores + softmax ----------------
// grid (S/64, H, B), block 512 (8 waves). Block: 64 q-rows x all 1024 cols.
// Wave w owns cols [w*128, w*128+128). K staged per depth-32 chunk in LDS
// (slot-rotation swizzle absorbed into staging's global address).
#define TQ 64
#define QS_LD 520  /* 512 + 8 pad: conflict-free fr-strided reads */
#define SMEM_SCORES (TQ * QS_LD * 2 + 1024 * 32 * 2 + 8 * TQ * 4)

__global__ __launch_bounds__(512, 1) void k_scores(const h16* __restrict__ Q,
                                                   const h16* __restrict__ Km,
                                                   const float* __restrict__ mask,
                                                   float* __restrict__ attn) {
  extern __shared__ __align__(16) char smem[];
  h16* Qs = (h16*)smem;                           // 64 x 520 fp16 = 66560 B
  h16* Ks = (h16*)(smem + TQ * QS_LD * 2);        // 1024 x 32 fp16 = 65536 B
  float* red = (float*)(smem + TQ * QS_LD * 2 + 1024 * 32 * 2);  // 8 x 64 f32

  const int tid = threadIdx.x, lane = tid & 63, wave = tid >> 6;
  const int qt = blockIdx.x, hh = blockIdx.y, b = blockIdx.z;
  const int q0 = qt * TQ;
  const int fr = lane & 15, qd = lane >> 4;
  const int ncol0 = wave * 128;

  // stage Q tile (64 x 512) into padded LDS with vector loads
  {
    const h16* Qg = Q + (size_t)(b * SEQ + q0) * HD + hh * DEP;
    for (int it = 0; it < 8; ++it) {
      int g = tid + it * 512;            // 0..4095
      int row = g >> 6, c8 = g & 63;
      h16x8 v = *(const h16x8*)(Qg + (size_t)row * HD + c8 * 8);
      *(h16x8*)(Qs + row * QS_LD + c8 * 8) = v;
    }
  }

  f32x4 acc[4][8];
  for (int i = 0; i < 4; ++i)
    for (int j = 0; j < 8; ++j) acc[i][j] = (f32x4)0.0f;

  for (int kc = 0; kc < 512; kc += 32) {
    __syncthreads();  // Ks reuse (also covers initial Qs staging)
    // stage K[0..1024)[kc..kc+32) : row n -> 4 slots of 16B, slot rotated by (n>>1)&3
    for (int c = 0; c < 8; ++c) {
      int nbase = wave * 128 + c * 16;
      int n = nbase + (lane >> 2);
      int s = lane & 3;
      int sp = (s - (n >> 1)) & 3;       // global depth-slot stored at phys slot s
      gload_lds16(Km + (size_t)(b * SEQ + n) * HD + hh * DEP + kc + sp * 8,
                  Ks + nbase * 32);
    }
    __syncthreads();
    h16x8 af[4];
    for (int i = 0; i < 4; ++i)
      af[i] = *(const h16x8*)(Qs + (i * 16 + fr) * QS_LD + kc + qd * 8);
#pragma unroll
    for (int j = 0; j < 8; ++j) {
      int n = ncol0 + j * 16 + fr;
      int slot = (qd + (n >> 1)) & 3;
      h16x8 bf = *(const h16x8*)(Ks + n * 32 + slot * 8);
      for (int i = 0; i < 4; ++i) acc[i][j] = MFMA16(af[i], bf, acc[i][j]);
    }
  }

  const float scale = 0.044194173824159216f;  // 1/sqrt(512)
  float rmax[4][4];
  for (int i = 0; i < 4; ++i)
    for (int r = 0; r < 4; ++r) rmax[i][r] = -3.4e38f;
  for (int i = 0; i < 4; ++i)
    for (int j = 0; j < 8; ++j)
      for (int r = 0; r < 4; ++r) {
        int lr = i * 16 + qd * 4 + r;
        int cg = ncol0 + j * 16 + fr;
        float v = acc[i][j][r] * scale +
                  mask[(size_t)(b * SEQ + q0 + lr) * SEQ + cg] * (-1e9f);
        acc[i][j][r] = v;
        rmax[i][r] = fmaxf(rmax[i][r], v);
      }
  for (int i = 0; i < 4; ++i)
    for (int r = 0; r < 4; ++r)
      for (int off = 1; off < 16; off <<= 1)
        rmax[i][r] = fmaxf(rmax[i][r], __shfl_xor(rmax[i][r], off, 64));
  __syncthreads();  // before writing red (Ks reads done anyway)
  if (fr == 0)
    for (int i = 0; i < 4; ++i)
      for (int r = 0; r < 4; ++r) red[wave * TQ + i * 16 + qd * 4 + r] = rmax[i][r];
  __syncthreads();
  float gmax[4][4];
  for (int i = 0; i < 4; ++i)
    for (int r = 0; r < 4; ++r) {
      int lr = i * 16 + qd * 4 + r;
      float m = red[lr];
      for (int w = 1; w < 8; ++w) m = fmaxf(m, red[w * TQ + lr]);
      gmax[i][r] = m;
    }
  __syncthreads();  // before reusing red for sums

  float rsum[4][4];
  for (int i = 0; i < 4; ++i)
    for (int r = 0; r < 4; ++r) rsum[i][r] = 0.f;
  for (int i = 0; i < 4; ++i)
    for (int j = 0; j < 8; ++j)
      for (int r = 0; r < 4; ++r) {
        float e = __expf(acc[i][j][r] - gmax[i][r]);
        acc[i][j][r] = e;
        rsum[i][r] += e;
      }
  for (int i = 0; i < 4; ++i)
    for (int r = 0; r < 4; ++r)
      for (int off = 1; off < 16; off <<= 1)
        rsum[i][r] += __shfl_xor(rsum[i][r], off, 64);
  if (fr == 0)
    for (int i = 0; i < 4; ++i)
      for (int r = 0; r < 4; ++r) red[wave * TQ + i * 16 + qd * 4 + r] = rsum[i][r];
  __syncthreads();

  float* ab = attn + (size_t)(b * NH + hh) * (size_t)(SEQ * SEQ);
  for (int i = 0; i < 4; ++i)
    for (int r = 0; r < 4; ++r) {
      int lr = i * 16 + qd * 4 + r;
      float tot = 0.f;
      for (int w = 0; w < 8; ++w) tot += red[w * TQ + lr];
      float inv = 1.0f / tot;
      for (int j = 0; j < 8; ++j)
        ab[(size_t)(q0 + lr) * SEQ + ncol0 + j * 16 + fr] = acc[i][j][r] * inv;
    }
}

// ---------------- PV GEMM: ctx = attn(fp32) @ V -> ctx fp16 (B,S,H*D) ----------------
__global__ __launch_bounds__(256) void k_gemm_pv(const float* __restrict__ P,
                                                 const h16* __restrict__ Vt,
                                                 h16* __restrict__ ctx) {
  __shared__ __align__(16) h16 As[128 * 64];
  __shared__ __align__(16) h16 Bs[128 * 64];
  const int tid = threadIdx.x, lane = tid & 63, wave = tid >> 6;
  const int wm = (wave >> 1) * 64, wn = (wave & 1) * 64;
  const int m0 = blockIdx.y * 128;   // q rows (x fastest shares A panel)
  const int n0 = blockIdx.x * 128;   // d cols
  const int bh = blockIdx.z;
  const float* Pb = P + (size_t)bh * (size_t)(SEQ * SEQ);
  const h16* Vb = Vt + (size_t)bh * (size_t)(DEP * SEQ);

  f32x4 acc[4][4];
  for (int i = 0; i < 4; ++i)
    for (int j = 0; j < 4; ++j) acc[i][j] = (f32x4)0.0f;

  const int arow = tid >> 1;
  const int acol = (tid & 1) * 32;
  const int lrow = lane >> 3, lcol = (lane & 7) * 8;
  const int fr = lane & 15, qd = lane >> 4;

  for (int k0 = 0; k0 < SEQ; k0 += 64) {
    __syncthreads();
    const float* src = Pb + (size_t)(m0 + arow) * SEQ + k0 + acol;
    for (int u = 0; u < 8; ++u) {
      float4 f = ((const float4*)src)[u];
      h16x4 pk = { f2h(f.x), f2h(f.y), f2h(f.z), f2h(f.w) };
      *(h16x4*)(As + arow * 64 + acol + u * 4) = pk;
    }
    for (int i = 0; i < 4; ++i) {
      int g = wave * 4 + i;
      int row = g * 8 + lrow;
      gload_lds16(Vb + (size_t)(n0 + row) * SEQ + k0 + lcol, Bs + g * 512);
    }
    __syncthreads();
    for (int kk = 0; kk < 64; kk += 32) {
      h16x8 af[4], bf[4];
      for (int i = 0; i < 4; ++i)
        af[i] = *(const h16x8*)(As + (wm + i * 16 + fr) * 64 + kk + qd * 8);
      for (int j = 0; j < 4; ++j)
        bf[j] = *(const h16x8*)(Bs + (wn + j * 16 + fr) * 64 + kk + qd * 8);
      for (int i = 0; i < 4; ++i)
        for (int j = 0; j < 4; ++j) acc[i][j] = MFMA16(af[i], bf[j], acc[i][j]);
    }
  }

  const int bb = bh >> 3, hh = bh & 7;
  for (int i = 0; i < 4; ++i)
    for (int j = 0; j < 4; ++j) {
      int s = m0 + wm + i * 16 + qd * 4;
      int d = n0 + wn + j * 16 + fr;
      for (int r = 0; r < 4; ++r)
        ctx[(size_t)(bb * SEQ + s + r) * HD + hh * DEP + d] = f2h(acc[i][j][r]);
    }
}

extern "C" void kernel_launch(void* const* d_in, const int* in_sizes, int n_in,
                              void* d_out, int out_size, void* d_ws, size_t ws_size,
                              hipStream_t stream) {
  const float* v_ip = (const float*)d_in[0];
  const float* k_ip = (const float*)d_in[1];
  const float* q_ip = (const float*)d_in[2];
  const float* mask = (const float*)d_in[3];
  const float* wq = (const float*)d_in[4];
  const float* bq = (const float*)d_in[5];
  const float* wk = (const float*)d_in[6];
  const float* bk = (const float*)d_in[7];
  const float* wv = (const float*)d_in[8];
  const float* bv = (const float*)d_in[9];
  const float* wo = (const float*)d_in[10];
  const float* bo = (const float*)d_in[11];

  char* ws = (char*)d_ws;
  h16* Qh  = (h16*)(ws + (size_t)0);          // 64 MB; reused as ctx after scores
  h16* Kh  = (h16*)(ws + (size_t)67108864);   // 64 MB
  h16* Vt  = (h16*)(ws + (size_t)134217728);  // 64 MB, layout (B,H,D,S)
  h16* xq  = (h16*)(ws + (size_t)201326592);  // 8 MB each
  h16* xk  = (h16*)(ws + (size_t)209715200);
  h16* xv  = (h16*)(ws + (size_t)218103808);
  h16* WqT = (h16*)(ws + (size_t)226492416);  // 4 MB each (N-major, k-contiguous)
  h16* WkT = (h16*)(ws + (size_t)230686720);
  h16* WvT = (h16*)(ws + (size_t)234881024);
  h16* WoT = (h16*)(ws + (size_t)239075328);
  h16* ctx = Qh;

  float* out = (float*)d_out;
  float* attn = out + (size_t)BS * DEP;

  // allow >64KB dynamic LDS for k_scores (immediate, capture-safe, idempotent)
  hipFuncSetAttribute((const void*)k_scores,
                      hipFuncAttributeMaxDynamicSharedMemorySize, SMEM_SCORES);

  k_conv3<<<dim3(4096, 3), 256, 0, stream>>>(q_ip, k_ip, v_ip, xq, xk, xv);
  k_transpose3<<<dim3(128, 16, 3), 256, 0, stream>>>(wq, wk, wv, WqT, WkT, WvT);
  k_transpose<<<dim3(16, 128), 256, 0, stream>>>(wo, WoT, 4096, 512);
  k_gemm_qkv<<<dim3(32, 64, 3), 256, 0, stream>>>(xq, xk, xv, WqT, WkT, WvT,
                                                  bq, bk, bv, Qh, Kh, Vt);
  k_scores<<<dim3(SEQ / TQ, NH, NB), 512, SMEM_SCORES, stream>>>(Qh, Kh, mask, attn);
  k_gemm_pv<<<dim3(4, 8, 64), 256, 0, stream>>>(attn, Vt, ctx);
  k_gemm_nt<2><<<dim3(4, 64), 256, 0, stream>>>(ctx, WoT, bo, out, 8192, 512, 4096, 512);
}

// Round 4
// 1034.486 us; speedup vs baseline: 1.1490x; 1.0029x over previous
//
#include <hip/hip_runtime.h>
#include <stdint.h>
#include <stddef.h>

// Narrow MHA: B=8, S=1024, D=512 (per head), H=8.
// fp16 MFMA GEMMs (16x16x32_f16), fp32 softmax, fp32 outputs (out, attn).
// R4: fix k_maskbits OOB (mask is (B,1,S,S)=8.4M floats -> 262144 words, 1 MB).
typedef _Float16 h16;
typedef __attribute__((ext_vector_type(4))) _Float16 h16x4;
typedef __attribute__((ext_vector_type(8))) _Float16 h16x8;
typedef __attribute__((ext_vector_type(4))) float f32x4;

#define MFMA16(a, b, c) __builtin_amdgcn_mfma_f32_16x16x32_f16((a), (b), (c), 0, 0, 0)

#define NB 8
#define SEQ 1024
#define DEP 512
#define NH 8
#define HD 4096  /* NH*DEP */
#define BS 8192  /* NB*SEQ */

static __device__ __forceinline__ void gload_lds16(const void* g, void* l) {
  __builtin_amdgcn_global_load_lds((__attribute__((address_space(1))) void*)(g),
                                   (__attribute__((address_space(3))) void*)(l),
                                   16, 0, 0);
}

static __device__ __forceinline__ h16 f2h(float f) { return (h16)f; }

// ---------------- fused fp32 -> fp16 for q,k,v ----------------
__global__ __launch_bounds__(256) void k_conv3(const float* __restrict__ q,
                                               const float* __restrict__ k,
                                               const float* __restrict__ v,
                                               h16* __restrict__ xq, h16* __restrict__ xk,
                                               h16* __restrict__ xv) {
  int z = blockIdx.y;
  const float* in = z == 0 ? q : (z == 1 ? k : v);
  h16* out = z == 0 ? xq : (z == 1 ? xk : xv);
  int i = blockIdx.x * 256 + threadIdx.x;
  float4 f = ((const float4*)in)[i];
  h16x4 o = { f2h(f.x), f2h(f.y), f2h(f.z), f2h(f.w) };
  ((h16x4*)out)[i] = o;
}

// ---------------- mask (0/1 fp32, B*S*S floats) -> bitmask (262144 uint32) ----------------
__global__ __launch_bounds__(256) void k_maskbits(const float* __restrict__ mask,
                                                  uint32_t* __restrict__ bits) {
  int g = blockIdx.x * 256 + threadIdx.x;  // 262,144 threads, 32 floats each
  const float4* mp = (const float4*)mask + (size_t)g * 8;
  uint32_t w = 0;
#pragma unroll
  for (int u = 0; u < 8; ++u) {
    float4 f = mp[u];
    w |= (f.x != 0.f ? 1u : 0u) << (u * 4);
    w |= (f.y != 0.f ? 1u : 0u) << (u * 4 + 1);
    w |= (f.z != 0.f ? 1u : 0u) << (u * 4 + 2);
    w |= (f.w != 0.f ? 1u : 0u) << (u * 4 + 3);
  }
  bits[g] = w;
}

// ---------------- transpose + convert: in (R x C) fp32 -> out (C x R) fp16 ----------------
__global__ __launch_bounds__(256) void k_transpose(const float* __restrict__ in,
                                                   h16* __restrict__ out, int R, int C) {
  __shared__ float t[32][33];
  int c0 = blockIdx.x * 32, r0 = blockIdx.y * 32;
  int tx = threadIdx.x & 31, ty = threadIdx.x >> 5;
  for (int p = 0; p < 4; ++p)
    t[ty + p * 8][tx] = in[(size_t)(r0 + ty + p * 8) * C + c0 + tx];
  __syncthreads();
  for (int p = 0; p < 4; ++p)
    out[(size_t)(c0 + ty + p * 8) * R + r0 + tx] = f2h(t[tx][ty + p * 8]);
}

__global__ __launch_bounds__(256) void k_transpose3(const float* __restrict__ wq,
                                                    const float* __restrict__ wk,
                                                    const float* __restrict__ wv,
                                                    h16* __restrict__ oq, h16* __restrict__ ok,
                                                    h16* __restrict__ ov) {
  __shared__ float t[32][33];
  int z = blockIdx.z;
  const float* in = z == 0 ? wq : (z == 1 ? wk : wv);
  h16* out = z == 0 ? oq : (z == 1 ? ok : ov);
  const int R = 512, C = 4096;
  int c0 = blockIdx.x * 32, r0 = blockIdx.y * 32;
  int tx = threadIdx.x & 31, ty = threadIdx.x >> 5;
  for (int p = 0; p < 4; ++p)
    t[ty + p * 8][tx] = in[(size_t)(r0 + ty + p * 8) * C + c0 + tx];
  __syncthreads();
  for (int p = 0; p < 4; ++p)
    out[(size_t)(c0 + ty + p * 8) * R + r0 + tx] = f2h(t[tx][ty + p * 8]);
}

// ---------------- merged QKV projection GEMM ----------------
__global__ __launch_bounds__(256) void k_gemm_qkv(
    const h16* __restrict__ xq, const h16* __restrict__ xk, const h16* __restrict__ xv,
    const h16* __restrict__ WqT, const h16* __restrict__ WkT, const h16* __restrict__ WvT,
    const float* __restrict__ bq, const float* __restrict__ bk, const float* __restrict__ bv,
    h16* __restrict__ Qh, h16* __restrict__ Kh, h16* __restrict__ Vt) {
  __shared__ __align__(16) h16 As[128 * 64];
  __shared__ __align__(16) h16 Bs[128 * 64];
  const int z = blockIdx.z;
  const h16* A = z == 0 ? xq : (z == 1 ? xk : xv);
  const h16* Bm = z == 0 ? WqT : (z == 1 ? WkT : WvT);
  const float* bias = z == 0 ? bq : (z == 1 ? bk : bv);
  const int K = 512;
  const int tid = threadIdx.x, lane = tid & 63, wave = tid >> 6;
  const int wm = (wave >> 1) * 64, wn = (wave & 1) * 64;
  const int m0 = blockIdx.y * 128;
  const int n0 = blockIdx.x * 128;

  f32x4 acc[4][4];
  for (int i = 0; i < 4; ++i)
    for (int j = 0; j < 4; ++j) acc[i][j] = (f32x4)0.0f;

  const int lrow = lane >> 3, lcol = (lane & 7) * 8;
  const int fr = lane & 15, qd = lane >> 4;

  for (int k0 = 0; k0 < K; k0 += 64) {
    __syncthreads();
    for (int i = 0; i < 4; ++i) {
      int g = wave * 4 + i;
      int row = g * 8 + lrow;
      gload_lds16(A + (size_t)(m0 + row) * K + k0 + lcol, As + g * 512);
      gload_lds16(Bm + (size_t)(n0 + row) * K + k0 + lcol, Bs + g * 512);
    }
    __syncthreads();
    for (int kk = 0; kk < 64; kk += 32) {
      h16x8 af[4], bf[4];
      for (int i = 0; i < 4; ++i)
        af[i] = *(const h16x8*)(As + (wm + i * 16 + fr) * 64 + kk + qd * 8);
      for (int j = 0; j < 4; ++j)
        bf[j] = *(const h16x8*)(Bs + (wn + j * 16 + fr) * 64 + kk + qd * 8);
      for (int i = 0; i < 4; ++i)
        for (int j = 0; j < 4; ++j) acc[i][j] = MFMA16(af[i], bf[j], acc[i][j]);
    }
  }

  h16* Cnat = z == 0 ? Qh : Kh;
  for (int i = 0; i < 4; ++i)
    for (int j = 0; j < 4; ++j) {
      int mbase = m0 + wm + i * 16 + qd * 4;
      int ncol = n0 + wn + j * 16 + fr;
      float bv2 = bias[ncol];
      if (z < 2) {
        for (int r = 0; r < 4; ++r)
          Cnat[(size_t)(mbase + r) * HD + ncol] = f2h(acc[i][j][r] + bv2);
      } else {
        int bb = mbase >> 10, ss = mbase & 1023;
        int hh = ncol >> 9, dd = ncol & 511;
        size_t addr = ((size_t)((bb * NH + hh) * DEP + dd)) * SEQ + ss;
        h16x4 pk = { f2h(acc[i][j][0] + bv2), f2h(acc[i][j][1] + bv2),
                     f2h(acc[i][j][2] + bv2), f2h(acc[i][j][3] + bv2) };
        *(h16x4*)(Vt + addr) = pk;
      }
    }
}

// ---------------- NT GEMM (out-projection): fp32 out ----------------
template <int OUT_MODE>
__global__ __launch_bounds__(256) void k_gemm_nt(const h16* __restrict__ A,
                                                 const h16* __restrict__ Bm,
                                                 const float* __restrict__ bias,
                                                 void* __restrict__ Cout,
                                                 int M, int N, int K, int ldc) {
  __shared__ __align__(16) h16 As[128 * 64];
  __shared__ __align__(16) h16 Bs[128 * 64];
  const int tid = threadIdx.x, lane = tid & 63, wave = tid >> 6;
  const int wm = (wave >> 1) * 64, wn = (wave & 1) * 64;
  const int m0 = blockIdx.y * 128;
  const int n0 = blockIdx.x * 128;

  f32x4 acc[4][4];
  for (int i = 0; i < 4; ++i)
    for (int j = 0; j < 4; ++j) acc[i][j] = (f32x4)0.0f;

  const int lrow = lane >> 3, lcol = (lane & 7) * 8;
  const int fr = lane & 15, qd = lane >> 4;

  for (int k0 = 0; k0 < K; k0 += 64) {
    __syncthreads();
    for (int i = 0; i < 4; ++i) {
      int g = wave * 4 + i;
      int row = g * 8 + lrow;
      gload_lds16(A + (size_t)(m0 + row) * K + k0 + lcol, As + g * 512);
      gload_lds16(Bm + (size_t)(n0 + row) * K + k0 + lcol, Bs + g * 512);
    }
    __syncthreads();
    for (int kk = 0; kk < 64; kk += 32) {
      h16x8 af[4], bf[4];
      for (int i = 0; i < 4; ++i)
        af[i] = *(const h16x8*)(As + (wm + i * 16 + fr) * 64 + kk + qd * 8);
      for (int j = 0; j < 4; ++j)
        bf[j] = *(const h16x8*)(Bs + (wn + j * 16 + fr) * 64 + kk + qd * 8);
      for (int i = 0; i < 4; ++i)
        for (int j = 0; j < 4; ++j) acc[i][j] = MFMA16(af[i], bf[j], acc[i][j]);
    }
  }

  for (int i = 0; i < 4; ++i)
    for (int j = 0; j < 4; ++j) {
      int mbase = m0 + wm + i * 16 + qd * 4;
      int ncol = n0 + wn + j * 16 + fr;
      float bv2 = bias ? bias[ncol] : 0.0f;
      float* Cp = (float*)Cout;
      for (int r = 0; r < 4; ++r)
        Cp[(size_t)(mbase + r) * ldc + ncol] = acc[i][j][r] + bv2;
    }
}

// ---------------- fused attention: QK^T + mask + softmax + attn-write + PV ----------------
// grid (S/64, H, B), 512 threads (8 waves). Wave w: score cols [w*128,(w+1)*128),
// PV d-cols [w*64,(w+1)*64). LDS: phase1 Qs[64x520]+Ks[1024x32 swizzled];
// phase2 Pa = P fp16 in 64-col-chunked A-layout [16][64][72] (+8 pad); red after Pa.
#define TQ 64
#define QS_LD 520
#define OFF_KS 66560                /* Qs: 64*520*2 */
#define PA_C64 4616                 /* h16 per 64-col chunk: 64*72+8 */
#define OFF_RED 147712              /* 16*PA_C64*2 */
#define CS_LD 536
#define SMEM_ATTN (OFF_RED + 2048)  /* 149760 B */

__global__ __launch_bounds__(512, 2) void k_attn(const h16* __restrict__ Q,
                                                 const h16* __restrict__ Km,
                                                 const uint32_t* __restrict__ bits,
                                                 const h16* __restrict__ Vtg,
                                                 float* __restrict__ attn,
                                                 h16* __restrict__ ctx) {
  extern __shared__ __align__(16) char smem[];
  h16* Qs = (h16*)smem;
  h16* Ks = (h16*)(smem + OFF_KS);
  h16* Pa = (h16*)smem;                 // phase 2 (overwrites Qs+Ks)
  h16* Cs = (h16*)smem;                 // ctx staging (overwrites Pa)
  float* red = (float*)(smem + OFF_RED);

  const int tid = threadIdx.x, lane = tid & 63, wave = tid >> 6;
  const int qt = blockIdx.x, hh = blockIdx.y, b = blockIdx.z;
  const int q0 = qt * TQ;
  const int fr = lane & 15, qd = lane >> 4;
  const int ncol0 = wave * 128;
  const int bh = b * NH + hh;

  // ---- phase 1: stage Q tile (64 x 512) into padded LDS ----
  {
    const h16* Qg = Q + (size_t)(b * SEQ + q0) * HD + hh * DEP;
    for (int it = 0; it < 8; ++it) {
      int g = tid + it * 512;
      int row = g >> 6, c8 = g & 63;
      *(h16x8*)(Qs + row * QS_LD + c8 * 8) = *(const h16x8*)(Qg + (size_t)row * HD + c8 * 8);
    }
  }

  f32x4 acc[4][8];
  for (int i = 0; i < 4; ++i)
    for (int j = 0; j < 8; ++j) acc[i][j] = (f32x4)0.0f;

  for (int kc = 0; kc < 512; kc += 32) {
    __syncthreads();
    // stage K rows [wave*128, +128) x depth [kc,kc+32), slot-rotation swizzled
    for (int c = 0; c < 8; ++c) {
      int nbase = wave * 128 + c * 16;
      int n = nbase + (lane >> 2);
      int s = lane & 3;
      int sp = (s - (n >> 1)) & 3;
      gload_lds16(Km + (size_t)(b * SEQ + n) * HD + hh * DEP + kc + sp * 8,
                  Ks + nbase * 32);
    }
    __syncthreads();
    h16x8 af[4];
    for (int i = 0; i < 4; ++i)
      af[i] = *(const h16x8*)(Qs + (i * 16 + fr) * QS_LD + kc + qd * 8);
#pragma unroll
    for (int j = 0; j < 8; ++j) {
      int n = ncol0 + j * 16 + fr;
      int slot = (qd + (n >> 1)) & 3;
      h16x8 bf = *(const h16x8*)(Ks + n * 32 + slot * 8);
      for (int i = 0; i < 4; ++i) acc[i][j] = MFMA16(af[i], bf, acc[i][j]);
    }
  }

  // ---- phase 1b: mask (bits) + softmax ----
  const float scale = 0.044194173824159216f;  // 1/sqrt(512)
  const uint32_t* bitp = bits + (size_t)(b * SEQ + q0) * 32 + wave * 4;
  float rmax[4][4];
#pragma unroll
  for (int i = 0; i < 4; ++i) {
    uint4 mwi[4];
    for (int r = 0; r < 4; ++r)
      mwi[r] = *(const uint4*)(bitp + (size_t)(i * 16 + qd * 4 + r) * 32);
    for (int r = 0; r < 4; ++r) rmax[i][r] = -3.4e38f;
#pragma unroll
    for (int j = 0; j < 8; ++j)
      for (int r = 0; r < 4; ++r) {
        uint32_t ww = (j >> 1) == 0 ? mwi[r].x
                    : (j >> 1) == 1 ? mwi[r].y
                    : (j >> 1) == 2 ? mwi[r].z : mwi[r].w;
        uint32_t m = (ww >> (fr + ((j & 1) << 4))) & 1u;
        float v = acc[i][j][r] * scale + (m ? -1e9f : 0.0f);
        acc[i][j][r] = v;
        rmax[i][r] = fmaxf(rmax[i][r], v);
      }
  }
  for (int i = 0; i < 4; ++i)
    for (int r = 0; r < 4; ++r)
      for (int off = 1; off < 16; off <<= 1)
        rmax[i][r] = fmaxf(rmax[i][r], __shfl_xor(rmax[i][r], off, 64));
  __syncthreads();  // all Qs/Ks reads done (protects later Pa overwrite too)
  if (fr == 0)
    for (int i = 0; i < 4; ++i)
      for (int r = 0; r < 4; ++r) red[wave * TQ + i * 16 + qd * 4 + r] = rmax[i][r];
  __syncthreads();
  float gmax[4][4];
  for (int i = 0; i < 4; ++i)
    for (int r = 0; r < 4; ++r) {
      int lr = i * 16 + qd * 4 + r;
      float m = red[lr];
      for (int w = 1; w < 8; ++w) m = fmaxf(m, red[w * TQ + lr]);
      gmax[i][r] = m;
    }
  __syncthreads();

  float rsum[4][4];
  for (int i = 0; i < 4; ++i)
    for (int r = 0; r < 4; ++r) rsum[i][r] = 0.f;
  for (int i = 0; i < 4; ++i)
    for (int j = 0; j < 8; ++j)
      for (int r = 0; r < 4; ++r) {
        float e = __expf(acc[i][j][r] - gmax[i][r]);
        acc[i][j][r] = e;
        rsum[i][r] += e;
      }
  for (int i = 0; i < 4; ++i)
    for (int r = 0; r < 4; ++r)
      for (int off = 1; off < 16; off <<= 1)
        rsum[i][r] += __shfl_xor(rsum[i][r], off, 64);
  if (fr == 0)
    for (int i = 0; i < 4; ++i)
      for (int r = 0; r < 4; ++r) red[wave * TQ + i * 16 + qd * 4 + r] = rsum[i][r];
  __syncthreads();

  // ---- phase 2a: normalize -> fp16 -> Pa (A-operand layout, 64-col chunks) ----
  // Pa element (row lr, col) at: (col>>6)*PA_C64 + lr*72 + (col&63)
  for (int i = 0; i < 4; ++i)
    for (int r = 0; r < 4; ++r) {
      int lr = i * 16 + qd * 4 + r;
      float tot = 0.f;
      for (int w = 0; w < 8; ++w) tot += red[w * TQ + lr];
      float inv = 1.0f / tot;
#pragma unroll
      for (int j = 0; j < 8; ++j) {
        int c64 = wave * 2 + (j >> 2);
        int coff = ((j & 3) << 4) + fr;
        Pa[c64 * PA_C64 + lr * 72 + coff] = f2h(acc[i][j][r] * inv);
      }
    }
  __syncthreads();  // Pa complete; all waves may now read any of it

  // ---- write attn (fp32) coalesced from Pa ----
  {
    int row = tid >> 3, p = tid & 7;
    float* ab = attn + (size_t)bh * (SEQ * (size_t)SEQ) + (size_t)(q0 + row) * SEQ;
#pragma unroll
    for (int cc = 0; cc < 4; ++cc) {
      int c2 = p * 4 + cc;                       // 32-col chunk 0..31
      const h16* src = Pa + (c2 >> 1) * PA_C64 + row * 72 + (c2 & 1) * 32;
      float* dst = ab + c2 * 32;
#pragma unroll
      for (int u = 0; u < 4; ++u) {
        h16x8 hv = *(const h16x8*)(src + u * 8);
        float4 lo = { (float)hv[0], (float)hv[1], (float)hv[2], (float)hv[3] };
        float4 hi = { (float)hv[4], (float)hv[5], (float)hv[6], (float)hv[7] };
        *(float4*)(dst + u * 8) = lo;
        *(float4*)(dst + u * 8 + 4) = hi;
      }
    }
  }

  // ---- phase 2b: PV. ctx_tile[64 q x 512 d] = P[64x1024] @ V_bh; wave owns 64 d ----
  const int d0 = wave * 64;
  const h16* Vb = Vtg + (size_t)bh * (DEP * (size_t)SEQ);
  f32x4 acc2[4][4];
  for (int i = 0; i < 4; ++i)
    for (int j = 0; j < 4; ++j) acc2[i][j] = (f32x4)0.0f;

  h16x8 bfn[4];
#pragma unroll
  for (int j = 0; j < 4; ++j)
    bfn[j] = *(const h16x8*)(Vb + (size_t)(d0 + j * 16 + fr) * SEQ + qd * 8);
  for (int c2 = 0; c2 < 32; ++c2) {
    h16x8 bf[4];
#pragma unroll
    for (int j = 0; j < 4; ++j) bf[j] = bfn[j];
    if (c2 < 31) {
#pragma unroll
      for (int j = 0; j < 4; ++j)
        bfn[j] = *(const h16x8*)(Vb + (size_t)(d0 + j * 16 + fr) * SEQ + (c2 + 1) * 32 + qd * 8);
    }
    h16x8 af2[4];
#pragma unroll
    for (int i = 0; i < 4; ++i)
      af2[i] = *(const h16x8*)(Pa + (c2 >> 1) * PA_C64 + (i * 16 + fr) * 72 + (c2 & 1) * 32 + qd * 8);
    for (int i = 0; i < 4; ++i)
      for (int j = 0; j < 4; ++j) acc2[i][j] = MFMA16(af2[i], bf[j], acc2[i][j]);
  }

  // ---- ctx epilogue: regs -> Cs -> coalesced global (ctx aliases Q tile of THIS block) ----
  __syncthreads();  // all Pa reads done before Cs overwrite
  for (int i = 0; i < 4; ++i)
    for (int j = 0; j < 4; ++j)
      for (int r = 0; r < 4; ++r)
        Cs[(i * 16 + qd * 4 + r) * CS_LD + d0 + j * 16 + fr] = f2h(acc2[i][j][r]);
  __syncthreads();
  {
    int row = tid >> 3, p = tid & 7;
    h16* cg = ctx + (size_t)(b * SEQ + q0 + row) * HD + hh * DEP + p * 64;
#pragma unroll
    for (int u = 0; u < 8; ++u)
      *(h16x8*)(cg + u * 8) = *(const h16x8*)(Cs + row * CS_LD + p * 64 + u * 8);
  }
}

extern "C" void kernel_launch(void* const* d_in, const int* in_sizes, int n_in,
                              void* d_out, int out_size, void* d_ws, size_t ws_size,
                              hipStream_t stream) {
  const float* v_ip = (const float*)d_in[0];
  const float* k_ip = (const float*)d_in[1];
  const float* q_ip = (const float*)d_in[2];
  const float* mask = (const float*)d_in[3];
  const float* wq = (const float*)d_in[4];
  const float* bq = (const float*)d_in[5];
  const float* wk = (const float*)d_in[6];
  const float* bk = (const float*)d_in[7];
  const float* wv = (const float*)d_in[8];
  const float* bv = (const float*)d_in[9];
  const float* wo = (const float*)d_in[10];
  const float* bo = (const float*)d_in[11];

  char* ws = (char*)d_ws;
  h16* Qh  = (h16*)(ws + (size_t)0);          // 64 MB; per-block overwritten by ctx
  h16* Kh  = (h16*)(ws + (size_t)67108864);   // 64 MB
  h16* Vt  = (h16*)(ws + (size_t)134217728);  // 64 MB, layout (B,H,D,S)
  h16* xq  = (h16*)(ws + (size_t)201326592);  // 8 MB each; xq reused as bits after qkv
  h16* xk  = (h16*)(ws + (size_t)209715200);
  h16* xv  = (h16*)(ws + (size_t)218103808);
  h16* WqT = (h16*)(ws + (size_t)226492416);  // 4 MB each
  h16* WkT = (h16*)(ws + (size_t)230686720);
  h16* WvT = (h16*)(ws + (size_t)234881024);
  h16* WoT = (h16*)(ws + (size_t)239075328);
  uint32_t* bits = (uint32_t*)xq;             // 1 MB (262144 words), written after qkv
  h16* ctx = Qh;

  float* out = (float*)d_out;
  float* attn = out + (size_t)BS * DEP;

  hipFuncSetAttribute((const void*)k_attn,
                      hipFuncAttributeMaxDynamicSharedMemorySize, SMEM_ATTN);

  k_conv3<<<dim3(4096, 3), 256, 0, stream>>>(q_ip, k_ip, v_ip, xq, xk, xv);
  k_transpose3<<<dim3(128, 16, 3), 256, 0, stream>>>(wq, wk, wv, WqT, WkT, WvT);
  k_transpose<<<dim3(16, 128), 256, 0, stream>>>(wo, WoT, 4096, 512);
  k_gemm_qkv<<<dim3(32, 64, 3), 256, 0, stream>>>(xq, xk, xv, WqT, WkT, WvT,
                                                  bq, bk, bv, Qh, Kh, Vt);
  // mask bits: B*S*S/32 = 262,144 words -> 1024 blocks x 256 threads
  k_maskbits<<<1024, 256, 0, stream>>>(mask, bits);
  k_attn<<<dim3(SEQ / TQ, NH, NB), 512, SMEM_ATTN, stream>>>(Qh, Kh, bits, Vt, attn, ctx);
  k_gemm_nt<2><<<dim3(4, 64), 256, 0, stream>>>(ctx, WoT, bo, out, 8192, 512, 4096, 512);
}